// Round 1
// baseline (44.220 us; speedup 1.0000x reference)
//
#include <hip/hip_runtime.h>
#include <hip/hip_bf16.h>

// Problem constants (from reference setup_inputs: b=4, s=4096, d=2048, CAPACITY=0.5)
#define BATCH 4
#define SEQ   4096
#define DMODEL 2048
#define KSEL  2048   // max(1, int(SEQ*0.5))

// ---------------------------------------------------------------------------
// Kernel 1: logits = x @ gate_w (fp64 accumulate), weights = sigmoid(logits)
// One 64-lane wave per row (b*s rows). 4 waves / 256-thread block.
// Each lane: 8 float4 loads of x (coalesced: lane i -> float4 index t*64+i),
// matching gate_w float4s (L1/L2-resident, 8 KiB), fp64 FMA accumulate,
// then 64-lane shuffle reduction.
// ---------------------------------------------------------------------------
__global__ __launch_bounds__(256) void logits_kernel(
    const float* __restrict__ x,
    const float* __restrict__ gate_w,
    float* __restrict__ logits,     // [BATCH*SEQ] in workspace
    float* __restrict__ weights)    // [BATCH*SEQ] -> d_out + BATCH*SEQ
{
    const int wave = threadIdx.x >> 6;
    const int lane = threadIdx.x & 63;
    const int row  = blockIdx.x * 4 + wave;          // 0 .. BATCH*SEQ-1

    const float4* xr = reinterpret_cast<const float4*>(x + (size_t)row * DMODEL);
    const float4* wr = reinterpret_cast<const float4*>(gate_w);

    double acc = 0.0;
#pragma unroll
    for (int t = 0; t < DMODEL / (64 * 4); ++t) {    // 8 iterations
        const int idx = t * 64 + lane;
        float4 xv = xr[idx];
        float4 wv = wr[idx];
        acc += (double)xv.x * (double)wv.x;
        acc += (double)xv.y * (double)wv.y;
        acc += (double)xv.z * (double)wv.z;
        acc += (double)xv.w * (double)wv.w;
    }
    // 64-lane butterfly-free down reduction
#pragma unroll
    for (int off = 32; off > 0; off >>= 1)
        acc += __shfl_down(acc, off, 64);

    if (lane == 0) {
        float l = (float)acc;
        logits[row]  = l;
        weights[row] = 1.0f / (1.0f + expf(-l));
    }
}

// ---------------------------------------------------------------------------
// Kernel 2: per-batch top-K mask via exact rank counting.
// grid = (BATCH, SEQ/64). Block = 256 threads.
// Block stages the full 4096-float row in LDS (16 KiB). Thread layout:
//   e = tid & 63  -> element index within this block's 64-element chunk
//   slice = tid>>6 -> quarter of the 4096-long comparison loop
// All lanes of a wave share `slice`, so the float4 LDS reads are wave-uniform
// (bank-conflict-free broadcast). Ranks combine via small LDS arrays.
// Tie-break matches jax.lax.top_k (ties resolved by lower index) via the
// rare-path recount of equal-with-lower-index.
// ---------------------------------------------------------------------------
__global__ __launch_bounds__(256) void select_kernel(
    const float* __restrict__ logits,
    float* __restrict__ mask)       // -> d_out + 0
{
    const int b    = blockIdx.x;     // batch
    const int eblk = blockIdx.y;     // element chunk (64 elements)

    __shared__ float L[SEQ];
    __shared__ int sh_gt[64][5];     // [e][slice], pad to 5 ints (odd stride)
    __shared__ int sh_eq[64][5];

    const float* row = logits + b * SEQ;
    for (int i = threadIdx.x; i < SEQ / 4; i += 256)
        reinterpret_cast<float4*>(L)[i] =
            reinterpret_cast<const float4*>(row)[i];
    __syncthreads();

    const int e     = threadIdx.x & 63;
    const int slice = threadIdx.x >> 6;
    const int i     = eblk * 64 + e;
    const float v   = L[i];

    int gt = 0, eq = 0;
    const int j0 = slice * (SEQ / 4);
#pragma unroll 4
    for (int j = j0; j < j0 + SEQ / 4; j += 4) {
        float4 q = *reinterpret_cast<const float4*>(&L[j]);
        gt += (q.x > v) + (q.y > v) + (q.z > v) + (q.w > v);
        eq += (q.x == v) + (q.y == v) + (q.z == v) + (q.w == v);
    }
    sh_gt[e][slice] = gt;
    sh_eq[e][slice] = eq;
    __syncthreads();

    if (slice == 0) {
        const int GT = sh_gt[e][0] + sh_gt[e][1] + sh_gt[e][2] + sh_gt[e][3];
        const int EQ = sh_eq[e][0] + sh_eq[e][1] + sh_eq[e][2] + sh_eq[e][3]; // includes self
        float m;
        if (GT >= KSEL) {
            m = 0.0f;
        } else if (EQ == 1) {
            m = 1.0f;                  // unique value, strictly inside top-K
        } else {
            // Rare tie path: jax top_k takes ties in increasing index order.
            int lower = 0;
            for (int j = 0; j < i; ++j) lower += (L[j] == v);
            m = (GT + lower < KSEL) ? 1.0f : 0.0f;
        }
        mask[b * SEQ + i] = m;
    }
}

// ---------------------------------------------------------------------------
// Kernel 3: aux_loss = unbiased variance of all weights (fp64 accumulate).
// Single 1024-thread block; weights (64 KiB) are L2-hot from kernel 1.
// ---------------------------------------------------------------------------
__global__ __launch_bounds__(1024) void finalize_kernel(
    const float* __restrict__ weights,
    float* __restrict__ aux)        // -> d_out + 2*BATCH*SEQ
{
    const int n = BATCH * SEQ;
    double s = 0.0, s2 = 0.0;
    for (int i = threadIdx.x; i < n; i += 1024) {
        double w = (double)weights[i];
        s  += w;
        s2 += w * w;
    }
#pragma unroll
    for (int off = 32; off > 0; off >>= 1) {
        s  += __shfl_down(s,  off, 64);
        s2 += __shfl_down(s2, off, 64);
    }
    __shared__ double sh[32];
    const int wid = threadIdx.x >> 6;
    const int lane = threadIdx.x & 63;
    if (lane == 0) { sh[wid] = s; sh[wid + 16] = s2; }
    __syncthreads();
    if (threadIdx.x == 0) {
        double S = 0.0, S2 = 0.0;
#pragma unroll
        for (int w = 0; w < 16; ++w) { S += sh[w]; S2 += sh[w + 16]; }
        double mean = S / n;
        double var  = (S2 - (double)n * mean * mean) / (double)(n - 1);
        *aux = (float)var;
    }
}

extern "C" void kernel_launch(void* const* d_in, const int* in_sizes, int n_in,
                              void* d_out, int out_size, void* d_ws, size_t ws_size,
                              hipStream_t stream) {
    const float* x      = (const float*)d_in[0];   // [4,4096,2048] f32
    const float* gate_w = (const float*)d_in[1];   // [2048] f32

    float* out   = (float*)d_out;
    float* mask    = out;                          // [4,4096,1]
    float* weights = out + BATCH * SEQ;            // [4,4096,1]
    float* aux     = out + 2 * BATCH * SEQ;        // [1]

    float* logits = (float*)d_ws;                  // [4*4096] scratch

    // K1: logits + weights  (one wave per row; 16384 rows / 4 waves per block)
    logits_kernel<<<dim3(BATCH * SEQ / 4), dim3(256), 0, stream>>>(
        x, gate_w, logits, weights);

    // K2: top-K mask per batch
    select_kernel<<<dim3(BATCH, SEQ / 64), dim3(256), 0, stream>>>(logits, mask);

    // K3: aux loss (variance)
    finalize_kernel<<<dim3(1), dim3(1024), 0, stream>>>(weights, aux);
}

// Round 2
// 41.964 us; speedup vs baseline: 1.0538x; 1.0538x over previous
//
#include <hip/hip_runtime.h>
#include <hip/hip_bf16.h>

// Problem constants (from reference setup_inputs: b=4, s=4096, d=2048, CAPACITY=0.5)
#define BATCH 4
#define SEQ   4096
#define DMODEL 2048
#define KSEL  2048   // max(1, int(SEQ*0.5))

// ---------------------------------------------------------------------------
// Kernel 1: logits = x @ gate_w (fp64 accumulate), weights = sigmoid(logits)
// One 64-lane wave per row (b*s rows). 4 waves / 256-thread block.
// 4 independent fp64 accumulators (one per float4 component) keep the
// dependency chain at 8 FMAs instead of 256 -> latency fully hidden behind
// the coalesced float4 stream; kernel should be HBM-bound.
// ---------------------------------------------------------------------------
__global__ __launch_bounds__(256) void logits_kernel(
    const float* __restrict__ x,
    const float* __restrict__ gate_w,
    float* __restrict__ logits,     // [BATCH*SEQ] in workspace
    float* __restrict__ weights)    // [BATCH*SEQ] -> d_out + BATCH*SEQ
{
    const int wave = threadIdx.x >> 6;
    const int lane = threadIdx.x & 63;
    const int row  = blockIdx.x * 4 + wave;          // 0 .. BATCH*SEQ-1

    const float4* xr = reinterpret_cast<const float4*>(x + (size_t)row * DMODEL);
    const float4* wr = reinterpret_cast<const float4*>(gate_w);

    double a0 = 0.0, a1 = 0.0, a2 = 0.0, a3 = 0.0;
#pragma unroll
    for (int t = 0; t < DMODEL / (64 * 4); ++t) {    // 8 iterations
        const int idx = t * 64 + lane;
        float4 xv = xr[idx];
        float4 wv = wr[idx];
        a0 += (double)xv.x * (double)wv.x;
        a1 += (double)xv.y * (double)wv.y;
        a2 += (double)xv.z * (double)wv.z;
        a3 += (double)xv.w * (double)wv.w;
    }
    double acc = (a0 + a1) + (a2 + a3);

    // 64-lane shuffle reduction
#pragma unroll
    for (int off = 32; off > 0; off >>= 1)
        acc += __shfl_down(acc, off, 64);

    if (lane == 0) {
        float l = (float)acc;
        logits[row]  = l;
        weights[row] = 1.0f / (1.0f + expf(-l));
    }
}

// ---------------------------------------------------------------------------
// Kernel 2 (merged select + finalize):
//   blocks 0 .. BATCH*64-1 : top-K mask via exact rank counting
//   block  BATCH*64        : aux_loss = unbiased variance of weights
// Mask blocks: b = blk/64, eblk = blk%64. Full 4096-float row staged in LDS
// (16 KiB); thread (e = tid&63, slice = tid>>6) -> each thread compares its
// element against one quarter of the row via wave-uniform float4 LDS reads
// (conflict-free broadcast). Tie-break matches jax.lax.top_k (lower index
// wins) via the rare-path recount.
// ---------------------------------------------------------------------------
__global__ __launch_bounds__(256) void select_finalize_kernel(
    const float* __restrict__ logits,
    const float* __restrict__ weights,
    float* __restrict__ mask,       // -> d_out + 0
    float* __restrict__ aux)        // -> d_out + 2*BATCH*SEQ
{
    if (blockIdx.x == BATCH * 64) {
        // ---- variance block (256 threads, 64 elems each, fp64) ----
        const int n = BATCH * SEQ;
        double s = 0.0, s2 = 0.0;
        for (int i = threadIdx.x; i < n; i += 256) {
            double w = (double)weights[i];
            s  += w;
            s2 += w * w;
        }
#pragma unroll
        for (int off = 32; off > 0; off >>= 1) {
            s  += __shfl_down(s,  off, 64);
            s2 += __shfl_down(s2, off, 64);
        }
        __shared__ double sh[8];
        const int wid  = threadIdx.x >> 6;
        const int lane = threadIdx.x & 63;
        if (lane == 0) { sh[wid] = s; sh[wid + 4] = s2; }
        __syncthreads();
        if (threadIdx.x == 0) {
            double S  = sh[0] + sh[1] + sh[2] + sh[3];
            double S2 = sh[4] + sh[5] + sh[6] + sh[7];
            double mean = S / n;
            double var  = (S2 - (double)n * mean * mean) / (double)(n - 1);
            *aux = (float)var;
        }
        return;
    }

    const int b    = blockIdx.x >> 6;    // batch
    const int eblk = blockIdx.x & 63;    // element chunk (64 elements)

    __shared__ float L[SEQ];
    __shared__ int sh_gt[64][5];         // [e][slice], stride 5 (odd) -> no conflicts
    __shared__ int sh_eq[64][5];

    const float* row = logits + b * SEQ;
    for (int i = threadIdx.x; i < SEQ / 4; i += 256)
        reinterpret_cast<float4*>(L)[i] =
            reinterpret_cast<const float4*>(row)[i];
    __syncthreads();

    const int e     = threadIdx.x & 63;
    const int slice = threadIdx.x >> 6;
    const int i     = eblk * 64 + e;
    const float v   = L[i];

    int gt = 0, eq = 0;
    const int j0 = slice * (SEQ / 4);
#pragma unroll 4
    for (int j = j0; j < j0 + SEQ / 4; j += 4) {
        float4 q = *reinterpret_cast<const float4*>(&L[j]);
        gt += (q.x > v) + (q.y > v) + (q.z > v) + (q.w > v);
        eq += (q.x == v) + (q.y == v) + (q.z == v) + (q.w == v);
    }
    sh_gt[e][slice] = gt;
    sh_eq[e][slice] = eq;
    __syncthreads();

    if (slice == 0) {
        const int GT = sh_gt[e][0] + sh_gt[e][1] + sh_gt[e][2] + sh_gt[e][3];
        const int EQ = sh_eq[e][0] + sh_eq[e][1] + sh_eq[e][2] + sh_eq[e][3]; // incl. self
        float m;
        if (GT >= KSEL) {
            m = 0.0f;
        } else if (EQ == 1) {
            m = 1.0f;                  // unique value, strictly inside top-K
        } else {
            // Rare tie path: jax top_k takes ties in increasing index order.
            int lower = 0;
            for (int j = 0; j < i; ++j) lower += (L[j] == v);
            m = (GT + lower < KSEL) ? 1.0f : 0.0f;
        }
        mask[b * SEQ + i] = m;
    }
}

extern "C" void kernel_launch(void* const* d_in, const int* in_sizes, int n_in,
                              void* d_out, int out_size, void* d_ws, size_t ws_size,
                              hipStream_t stream) {
    const float* x      = (const float*)d_in[0];   // [4,4096,2048] f32
    const float* gate_w = (const float*)d_in[1];   // [2048] f32

    float* out     = (float*)d_out;
    float* mask    = out;                          // [4,4096,1]
    float* weights = out + BATCH * SEQ;            // [4,4096,1]
    float* aux     = out + 2 * BATCH * SEQ;        // [1]

    float* logits = (float*)d_ws;                  // [4*4096] scratch

    // K1: logits + weights  (one wave per row; 16384 rows / 4 waves per block)
    logits_kernel<<<dim3(BATCH * SEQ / 4), dim3(256), 0, stream>>>(
        x, gate_w, logits, weights);

    // K2: top-K mask per batch + variance (one extra block)
    select_finalize_kernel<<<dim3(BATCH * 64 + 1), dim3(256), 0, stream>>>(
        logits, weights, mask, aux);
}